// Round 5
// baseline (246.201 us; speedup 1.0000x reference)
//
#include <hip/hip_runtime.h>
#include <hip/hip_bf16.h>
#include <math.h>

#define N_TOK 8192
#define HDIM  1024
#define NE    8
#define TILE  128
#define BK    32
#define KITER (HDIM / BK)          // 32
#define NCONV 8192                 // convert_w blocks
#define NGATE (N_TOK / 4)          // gate blocks (4 tokens each)

typedef __attribute__((ext_vector_type(8))) short bf16x8;
typedef __attribute__((ext_vector_type(4))) float f32x4;
typedef unsigned short u16;

__device__ __forceinline__ u16 f2bf(float f) {
    union { float f; unsigned u; } v; v.f = f;
    unsigned r = v.u + 0x7FFFu + ((v.u >> 16) & 1u);   // round-to-nearest-even
    return (u16)(r >> 16);
}

__device__ __forceinline__ void gld_lds16(const void* g, void* lds) {
    __builtin_amdgcn_global_load_lds(
        (const __attribute__((address_space(1))) unsigned int*)g,
        (__attribute__((address_space(3))) unsigned int*)lds,
        16, 0, 0);
}

// ---- prep: blocks [0,NGATE) gate+x->bf16 (long, start first); rest convert expert_w ----
__global__ __launch_bounds__(256)
void prep_kernel(const float* __restrict__ w, u16* __restrict__ wbf,
                 const float* __restrict__ x,
                 const float* __restrict__ gate_w,
                 const float* __restrict__ gate_b,
                 u16* __restrict__ xbf,
                 int* __restrict__ eids,       // [N_TOK] e0 | e1<<8
                 float2* __restrict__ gatesv)  // [N_TOK] (g0,g1)
{
    int bid = blockIdx.x;
    if (bid >= NGATE) {
        size_t i = (size_t)(bid - NGATE) * 256 + threadIdx.x;   // float4 index
        float4 v = ((const float4*)w)[i];
        ushort4 b;
        b.x = f2bf(v.x); b.y = f2bf(v.y); b.z = f2bf(v.z); b.w = f2bf(v.w);
        ((ushort4*)wbf)[i] = b;
        return;
    }
    int wave = threadIdx.x >> 6, lane = threadIdx.x & 63;
    int t = bid * 4 + wave;
    const float4* xt = (const float4*)(x + (size_t)t * HDIM);
    ushort4* xb = (ushort4*)(xbf + (size_t)t * HDIM);

    float acc[NE];
#pragma unroll
    for (int e = 0; e < NE; ++e) acc[e] = 0.f;

#pragma unroll
    for (int i = 0; i < 4; ++i) {
        int f = i * 64 + lane;
        float4 v = xt[f];
        ushort4 b;
        b.x = f2bf(v.x); b.y = f2bf(v.y); b.z = f2bf(v.z); b.w = f2bf(v.w);
        xb[f] = b;
#pragma unroll
        for (int e = 0; e < NE; ++e) {
            float4 wv = ((const float4*)(gate_w + e * HDIM))[f];
            acc[e] += v.x * wv.x + v.y * wv.y + v.z * wv.z + v.w * wv.w;
        }
    }
#pragma unroll
    for (int e = 0; e < NE; ++e)
        for (int off = 32; off > 0; off >>= 1)
            acc[e] += __shfl_down(acc[e], off);

    if (lane == 0) {
        float logit[NE];
        float mx = -1e30f;
#pragma unroll
        for (int e = 0; e < NE; ++e) {
            logit[e] = acc[e] + gate_b[e];
            mx = fmaxf(mx, logit[e]);
        }
        float p[NE], s = 0.f;
#pragma unroll
        for (int e = 0; e < NE; ++e) { p[e] = expf(logit[e] - mx); s += p[e]; }
        float inv = 1.f / s;
        int i0 = 0;
#pragma unroll
        for (int e = 1; e < NE; ++e) if (logit[e] > logit[i0]) i0 = e;
        int i1 = (i0 == 0) ? 1 : 0;
#pragma unroll
        for (int e = 0; e < NE; ++e) if (e != i0 && logit[e] > logit[i1]) i1 = e;

        eids[t]   = i0 | (i1 << 8);
        gatesv[t] = make_float2(p[i0] * inv, p[i1] * inv);
    }
}

// ---- compact: single block, hist+rank+scatter (16 sub-histograms) ----
__global__ __launch_bounds__(1024)
void compact_kernel(const int* __restrict__ eids,
                    const float2* __restrict__ gatesv,
                    int* __restrict__ tok_list, float* __restrict__ gate_list,
                    int* __restrict__ counts)
{
    __shared__ int lh[16][NE];
    __shared__ int lbase[16][NE];
    int tid = threadIdx.x;
    if (tid < 16 * NE) ((int*)lh)[tid] = 0;
    __syncthreads();
    int bucket = tid & 15;

    int e0v[8], e1v[8], r0v[8], r1v[8];
    float2 gv[8];
#pragma unroll
    for (int it = 0; it < 8; ++it) {
        int t = it * 1024 + tid;
        int ee = eids[t];
        e0v[it] = ee & 255; e1v[it] = (ee >> 8) & 255;
        gv[it] = gatesv[t];
        r0v[it] = atomicAdd(&lh[bucket][e0v[it]], 1);
        r1v[it] = atomicAdd(&lh[bucket][e1v[it]], 1);
    }
    __syncthreads();
    if (tid < NE) {
        int run = 0;
        for (int b = 0; b < 16; ++b) { lbase[b][tid] = run; run += lh[b][tid]; }
        counts[tid] = run;
    }
    __syncthreads();
#pragma unroll
    for (int it = 0; it < 8; ++it) {
        int t = it * 1024 + tid;
        int p0 = lbase[bucket][e0v[it]] + r0v[it];
        tok_list[e0v[it] * N_TOK + p0]  = t * 2;        // token*2 + slot
        gate_list[e0v[it] * N_TOK + p0] = gv[it].x;
        int p1 = lbase[bucket][e1v[it]] + r1v[it];
        tok_list[e1v[it] * N_TOK + p1]  = t * 2 + 1;
        gate_list[e1v[it] * N_TOK + p1] = gv[it].y;
    }
}

// ---- grouped per-expert GEMM: double-buffered async staging, raw vmcnt waits ----
// Per buffer: 512 slots of 16B. Slot s holds (row r = s>>2, global chunk (s&3)^((r>>1)&3)).
// Fragment read (row r, kchunk q) -> slot r*4 + (q^((r>>1)&3)): 2-way bank aliasing (free).
// Staging wave-instr: 16 rows x 64B contiguous -> 16 cache lines, sequential.
__global__ __launch_bounds__(256)
void moe_gemm_kernel(const u16* __restrict__ xbf,
                     const u16* __restrict__ wbf,
                     const float* __restrict__ expert_b,
                     const int* __restrict__ counts,
                     const int* __restrict__ tok_list,
                     const float* __restrict__ gate_list,
                     float* __restrict__ out,      // slot0 partials
                     float* __restrict__ part1)    // slot1 partials
{
    int e   = blockIdx.z;
    int cnt = counts[e];
    int m0  = blockIdx.x * TILE;
    if (m0 >= cnt) return;
    int n0  = blockIdx.y * TILE;

    __shared__ __align__(16) u16 As[2][512 * 8];   // 2 x 8 KB
    __shared__ __align__(16) u16 Bs[2][512 * 8];   // 2 x 8 KB

    int tid = threadIdx.x;
    int w = tid >> 6, l = tid & 63;

    // staging addresses: call j in {0,1}: slot s = j*256 + tid
    const u16* aP[2];
    const u16* bP[2];
#pragma unroll
    for (int j = 0; j < 2; ++j) {
        int s = j * 256 + tid;
        int r = s >> 2;
        int cs = (s & 3) ^ ((r >> 1) & 3);
        int tr = m0 + r; if (tr > cnt - 1) tr = cnt - 1;   // dup rows discarded in epilogue
        int lst = tok_list[e * N_TOK + tr];
        aP[j] = xbf + (size_t)(lst >> 1) * HDIM + cs * 8;
        bP[j] = wbf + (size_t)(e * HDIM + n0 + r) * HDIM + cs * 8;
    }

    int wm = (w >> 1) * 64, wn = (w & 1) * 64;
    int lrow = l & 15, quad = l >> 4;
    int swz = (lrow >> 1) & 3;     // row-dependent chunk swizzle (rows differ by mult of 16)
    int cx = quad ^ swz;           // lane's LDS chunk within a row

    f32x4 acc[4][4];
#pragma unroll
    for (int mi = 0; mi < 4; ++mi)
#pragma unroll
        for (int ni = 0; ni < 4; ++ni)
            acc[mi][ni] = (f32x4){0.f, 0.f, 0.f, 0.f};

    // prologue: stage iter 0 into buffer 0
#pragma unroll
    for (int j = 0; j < 2; ++j) {
        gld_lds16(aP[j], &As[0][(j * 256 + w * 64) * 8]);
        gld_lds16(bP[j], &Bs[0][(j * 256 + w * 64) * 8]);
    }

    for (int i = 0; i < KITER; ++i) {
        int p = i & 1;
        if (i + 1 < KITER) {
            int k1 = (i + 1) * BK;
#pragma unroll
            for (int j = 0; j < 2; ++j) {
                gld_lds16(aP[j] + k1, &As[1 - p][(j * 256 + w * 64) * 8]);
                gld_lds16(bP[j] + k1, &Bs[1 - p][(j * 256 + w * 64) * 8]);
            }
            asm volatile("s_waitcnt vmcnt(4)" ::: "memory");
        } else {
            asm volatile("s_waitcnt vmcnt(0)" ::: "memory");
        }
        __builtin_amdgcn_s_barrier();

        bf16x8 af[4], bfr[4];
#pragma unroll
        for (int ii = 0; ii < 4; ++ii) {
            int ra = wm + ii * 16 + lrow;
            int rb = wn + ii * 16 + lrow;
            af[ii]  = *(const bf16x8*)(&As[p][(ra * 4 + cx) * 8]);
            bfr[ii] = *(const bf16x8*)(&Bs[p][(rb * 4 + cx) * 8]);
        }
#pragma unroll
        for (int mi = 0; mi < 4; ++mi)
#pragma unroll
            for (int ni = 0; ni < 4; ++ni)
                acc[mi][ni] = __builtin_amdgcn_mfma_f32_16x16x32_bf16(
                    af[mi], bfr[ni], acc[mi][ni], 0, 0, 0);

        asm volatile("" ::: "memory");
        __builtin_amdgcn_s_barrier();   // reads of buf p done before it is re-staged
    }

    // epilogue: bias + gate, plain stores to (token,slot) partial rows
#pragma unroll
    for (int mi = 0; mi < 4; ++mi) {
#pragma unroll
        for (int rr = 0; rr < 4; ++rr) {
            int listRow = m0 + wm + mi * 16 + quad * 4 + rr;
            if (listRow < cnt) {
                int   lst = tok_list[e * N_TOK + listRow];
                float g   = gate_list[e * N_TOK + listRow];
                float* dst = ((lst & 1) ? part1 : out) + (size_t)(lst >> 1) * HDIM;
#pragma unroll
                for (int ni = 0; ni < 4; ++ni) {
                    int col = n0 + wn + ni * 16 + lrow;
                    dst[col] = (acc[mi][ni][rr] + expert_b[e * HDIM + col]) * g;
                }
            }
        }
    }
}

// ---- combine: out += part1 ----
__global__ __launch_bounds__(256)
void combine_kernel(float* __restrict__ out, const float* __restrict__ part1) {
    size_t i = (size_t)blockIdx.x * 256 + threadIdx.x;
    float4 a = ((const float4*)out)[i];
    float4 b = ((const float4*)part1)[i];
    a.x += b.x; a.y += b.y; a.z += b.z; a.w += b.w;
    ((float4*)out)[i] = a;
}

extern "C" void kernel_launch(void* const* d_in, const int* in_sizes, int n_in,
                              void* d_out, int out_size, void* d_ws, size_t ws_size,
                              hipStream_t stream)
{
    const float* x        = (const float*)d_in[0];
    const float* gate_w   = (const float*)d_in[1];
    const float* gate_b   = (const float*)d_in[2];
    const float* expert_w = (const float*)d_in[3];
    const float* expert_b = (const float*)d_in[4];
    float* out = (float*)d_out;

    char* ws = (char*)d_ws;
    int*    eids      = (int*)(ws);                         // 32 KB
    float2* gatesv    = (float2*)(ws + (64 << 10));         // 64 KB
    int*    counts    = (int*)(ws + (132 << 10));           // 256 B
    int*    tok_list  = (int*)(ws + (136 << 10));           // 256 KB
    float*  gate_list = (float*)(ws + (136 << 10) + NE * N_TOK * 4); // 256 KB
    u16*    xbf       = (u16*)(ws + (1 << 20));             // 16 MB
    u16*    wbf       = xbf + (size_t)N_TOK * HDIM;         // 16 MB
    float*  part1     = (float*)(ws + (33u << 20));         // 32 MB

    prep_kernel<<<NCONV + NGATE, 256, 0, stream>>>(expert_w, wbf, x, gate_w, gate_b,
                                                   xbf, eids, gatesv);
    compact_kernel<<<1, 1024, 0, stream>>>(eids, gatesv, tok_list, gate_list, counts);

    dim3 grid(N_TOK / TILE, HDIM / TILE, NE);   // empty tiles early-exit
    moe_gemm_kernel<<<grid, 256, 0, stream>>>(xbf, wbf, expert_b,
                                              counts, tok_list, gate_list, out, part1);

    combine_kernel<<<N_TOK * HDIM / 4 / 256, 256, 0, stream>>>(out, part1);
}

// Round 6
// 216.235 us; speedup vs baseline: 1.1386x; 1.1386x over previous
//
#include <hip/hip_runtime.h>
#include <hip/hip_bf16.h>
#include <math.h>

#define N_TOK 8192
#define HDIM  1024
#define NE    8
#define TILE  128
#define BK    64
#define NCONV 8192                 // convert_w blocks
#define NGATE (N_TOK / 4)          // gate blocks (4 tokens each)

typedef __attribute__((ext_vector_type(8))) short bf16x8;
typedef __attribute__((ext_vector_type(4))) float f32x4;
typedef unsigned short u16;

__device__ __forceinline__ u16 f2bf(float f) {
    union { float f; unsigned u; } v; v.f = f;
    unsigned r = v.u + 0x7FFFu + ((v.u >> 16) & 1u);   // round-to-nearest-even
    return (u16)(r >> 16);
}

__device__ __forceinline__ void gld_lds16(const void* g, void* lds) {
    __builtin_amdgcn_global_load_lds(
        (const __attribute__((address_space(1))) unsigned int*)g,
        (__attribute__((address_space(3))) unsigned int*)lds,
        16, 0, 0);
}

// ---- prep: blocks [0,NGATE) gate+x->bf16 (long, start first); rest convert expert_w ----
__global__ __launch_bounds__(256)
void prep_kernel(const float* __restrict__ w, u16* __restrict__ wbf,
                 const float* __restrict__ x,
                 const float* __restrict__ gate_w,
                 const float* __restrict__ gate_b,
                 u16* __restrict__ xbf,
                 int* __restrict__ eids,       // [N_TOK] e0 | e1<<8
                 float2* __restrict__ gatesv)  // [N_TOK] (g0,g1)
{
    int bid = blockIdx.x;
    if (bid >= NGATE) {
        size_t i = (size_t)(bid - NGATE) * 256 + threadIdx.x;   // float4 index
        float4 v = ((const float4*)w)[i];
        ushort4 b;
        b.x = f2bf(v.x); b.y = f2bf(v.y); b.z = f2bf(v.z); b.w = f2bf(v.w);
        ((ushort4*)wbf)[i] = b;
        return;
    }
    int wave = threadIdx.x >> 6, lane = threadIdx.x & 63;
    int t = bid * 4 + wave;
    const float4* xt = (const float4*)(x + (size_t)t * HDIM);
    ushort4* xb = (ushort4*)(xbf + (size_t)t * HDIM);

    float acc[NE];
#pragma unroll
    for (int e = 0; e < NE; ++e) acc[e] = 0.f;

#pragma unroll
    for (int i = 0; i < 4; ++i) {
        int f = i * 64 + lane;
        float4 v = xt[f];
        ushort4 b;
        b.x = f2bf(v.x); b.y = f2bf(v.y); b.z = f2bf(v.z); b.w = f2bf(v.w);
        xb[f] = b;
#pragma unroll
        for (int e = 0; e < NE; ++e) {
            float4 wv = ((const float4*)(gate_w + e * HDIM))[f];
            acc[e] += v.x * wv.x + v.y * wv.y + v.z * wv.z + v.w * wv.w;
        }
    }
#pragma unroll
    for (int e = 0; e < NE; ++e)
        for (int off = 32; off > 0; off >>= 1)
            acc[e] += __shfl_down(acc[e], off);

    if (lane == 0) {
        float logit[NE];
        float mx = -1e30f;
#pragma unroll
        for (int e = 0; e < NE; ++e) {
            logit[e] = acc[e] + gate_b[e];
            mx = fmaxf(mx, logit[e]);
        }
        float p[NE], s = 0.f;
#pragma unroll
        for (int e = 0; e < NE; ++e) { p[e] = expf(logit[e] - mx); s += p[e]; }
        float inv = 1.f / s;
        int i0 = 0;
#pragma unroll
        for (int e = 1; e < NE; ++e) if (logit[e] > logit[i0]) i0 = e;
        int i1 = (i0 == 0) ? 1 : 0;
#pragma unroll
        for (int e = 0; e < NE; ++e) if (e != i0 && logit[e] > logit[i1]) i1 = e;

        eids[t]   = i0 | (i1 << 8);
        gatesv[t] = make_float2(p[i0] * inv, p[i1] * inv);
    }
}

// ---- compact: single block, hist+rank+scatter (16 sub-histograms) ----
__global__ __launch_bounds__(1024)
void compact_kernel(const int* __restrict__ eids,
                    const float2* __restrict__ gatesv,
                    int* __restrict__ tok_list, float* __restrict__ gate_list,
                    int* __restrict__ counts)
{
    __shared__ int lh[16][NE];
    __shared__ int lbase[16][NE];
    int tid = threadIdx.x;
    if (tid < 16 * NE) ((int*)lh)[tid] = 0;
    __syncthreads();
    int bucket = tid & 15;

    int e0v[8], e1v[8], r0v[8], r1v[8];
    float2 gv[8];
#pragma unroll
    for (int it = 0; it < 8; ++it) {
        int t = it * 1024 + tid;
        int ee = eids[t];
        e0v[it] = ee & 255; e1v[it] = (ee >> 8) & 255;
        gv[it] = gatesv[t];
        r0v[it] = atomicAdd(&lh[bucket][e0v[it]], 1);
        r1v[it] = atomicAdd(&lh[bucket][e1v[it]], 1);
    }
    __syncthreads();
    if (tid < NE) {
        int run = 0;
        for (int b = 0; b < 16; ++b) { lbase[b][tid] = run; run += lh[b][tid]; }
        counts[tid] = run;
    }
    __syncthreads();
#pragma unroll
    for (int it = 0; it < 8; ++it) {
        int t = it * 1024 + tid;
        int p0 = lbase[bucket][e0v[it]] + r0v[it];
        tok_list[e0v[it] * N_TOK + p0]  = t * 2;        // token*2 + slot
        gate_list[e0v[it] * N_TOK + p0] = gv[it].x;
        int p1 = lbase[bucket][e1v[it]] + r1v[it];
        tok_list[e1v[it] * N_TOK + p1]  = t * 2 + 1;
        gate_list[e1v[it] * N_TOK + p1] = gv[it].y;
    }
}

// ---- grouped per-expert GEMM: r4 K-loop + XCD-locality block remap ----
// 1-D grid of 4096. Group of 64 consecutive bids: e = grp>>3, m_tile = (grp&7)*8 + (bid&7),
// n_tile = (bid>>3)&7. XCD = bid%8 (empirical round-robin) => all 8 n-tiles of one m-tile
// land on ONE XCD -> gathered A-tile fetched into that XCD's L2 once, reused 8x.
// LDS: 1024 slots of 16B per matrix. Slot s holds (row = s>>3, chunk = (s&7)^(row&7)).
__global__ __launch_bounds__(256)
void moe_gemm_kernel(const u16* __restrict__ xbf,
                     const u16* __restrict__ wbf,
                     const float* __restrict__ expert_b,
                     const int* __restrict__ counts,
                     const int* __restrict__ tok_list,
                     const float* __restrict__ gate_list,
                     float* __restrict__ out,      // slot0 partials
                     float* __restrict__ part1)    // slot1 partials
{
    int bid = blockIdx.x;
    int grp = bid >> 6;
    int e   = grp >> 3;
    int cnt = counts[e];
    int m0  = (((grp & 7) << 3) | (bid & 7)) * TILE;
    if (m0 >= cnt) return;
    int n0  = ((bid >> 3) & 7) * TILE;

    __shared__ __align__(16) u16 As[1024 * 8];   // 16 KB
    __shared__ __align__(16) u16 Bs[1024 * 8];   // 16 KB

    int tid = threadIdx.x;
    int w = tid >> 6, l = tid & 63;

    const u16* aP[4];
    const u16* bP[4];
#pragma unroll
    for (int j = 0; j < 4; ++j) {
        int s = j * 256 + w * 64 + l;
        int r = s >> 3;
        int cs = (s & 7) ^ (r & 7);
        int tr = m0 + r; if (tr > cnt - 1) tr = cnt - 1;   // dup rows discarded in epilogue
        int lst = tok_list[e * N_TOK + tr];
        aP[j] = xbf + (size_t)(lst >> 1) * HDIM + cs * 8;
        bP[j] = wbf + (size_t)(e * HDIM + n0 + r) * HDIM + cs * 8;
    }

    int wm = (w >> 1) * 64, wn = (w & 1) * 64;
    int lrow = l & 15, quad = l >> 4;
    int cxbase = lrow & 7;           // row&7 for all fragment rows this lane touches

    f32x4 acc[4][4];
#pragma unroll
    for (int mi = 0; mi < 4; ++mi)
#pragma unroll
        for (int ni = 0; ni < 4; ++ni)
            acc[mi][ni] = (f32x4){0.f, 0.f, 0.f, 0.f};

    for (int k0 = 0; k0 < HDIM; k0 += BK) {
#pragma unroll
        for (int j = 0; j < 4; ++j) {
            gld_lds16(aP[j] + k0, As + (j * 256 + w * 64) * 8);
            gld_lds16(bP[j] + k0, Bs + (j * 256 + w * 64) * 8);
        }
        __syncthreads();

#pragma unroll
        for (int t2 = 0; t2 < 2; ++t2) {
            int cx = (t2 * 4 + quad) ^ cxbase;   // swizzled chunk for this lane
            bf16x8 af[4], bfr[4];
#pragma unroll
            for (int i = 0; i < 4; ++i) {
                int ra = wm + i * 16 + lrow;
                int rb = wn + i * 16 + lrow;
                af[i]  = *(const bf16x8*)(As + (ra * 8 + cx) * 8);
                bfr[i] = *(const bf16x8*)(Bs + (rb * 8 + cx) * 8);
            }
#pragma unroll
            for (int mi = 0; mi < 4; ++mi)
#pragma unroll
                for (int ni = 0; ni < 4; ++ni)
                    acc[mi][ni] = __builtin_amdgcn_mfma_f32_16x16x32_bf16(
                        af[mi], bfr[ni], acc[mi][ni], 0, 0, 0);
        }
        __syncthreads();
    }

    // epilogue: bias + gate, plain stores to (token,slot) partial rows
#pragma unroll
    for (int mi = 0; mi < 4; ++mi) {
#pragma unroll
        for (int rr = 0; rr < 4; ++rr) {
            int listRow = m0 + wm + mi * 16 + quad * 4 + rr;
            if (listRow < cnt) {
                int   lst = tok_list[e * N_TOK + listRow];
                float g   = gate_list[e * N_TOK + listRow];
                float* dst = ((lst & 1) ? part1 : out) + (size_t)(lst >> 1) * HDIM;
#pragma unroll
                for (int ni = 0; ni < 4; ++ni) {
                    int col = n0 + wn + ni * 16 + lrow;
                    dst[col] = (acc[mi][ni][rr] + expert_b[e * HDIM + col]) * g;
                }
            }
        }
    }
}

// ---- combine: out += part1 ----
__global__ __launch_bounds__(256)
void combine_kernel(float* __restrict__ out, const float* __restrict__ part1) {
    size_t i = (size_t)blockIdx.x * 256 + threadIdx.x;
    float4 a = ((const float4*)out)[i];
    float4 b = ((const float4*)part1)[i];
    a.x += b.x; a.y += b.y; a.z += b.z; a.w += b.w;
    ((float4*)out)[i] = a;
}

extern "C" void kernel_launch(void* const* d_in, const int* in_sizes, int n_in,
                              void* d_out, int out_size, void* d_ws, size_t ws_size,
                              hipStream_t stream)
{
    const float* x        = (const float*)d_in[0];
    const float* gate_w   = (const float*)d_in[1];
    const float* gate_b   = (const float*)d_in[2];
    const float* expert_w = (const float*)d_in[3];
    const float* expert_b = (const float*)d_in[4];
    float* out = (float*)d_out;

    char* ws = (char*)d_ws;
    int*    eids      = (int*)(ws);                         // 32 KB
    float2* gatesv    = (float2*)(ws + (64 << 10));         // 64 KB
    int*    counts    = (int*)(ws + (132 << 10));           // 256 B
    int*    tok_list  = (int*)(ws + (136 << 10));           // 256 KB
    float*  gate_list = (float*)(ws + (136 << 10) + NE * N_TOK * 4); // 256 KB
    u16*    xbf       = (u16*)(ws + (1 << 20));             // 16 MB
    u16*    wbf       = xbf + (size_t)N_TOK * HDIM;         // 16 MB
    float*  part1     = (float*)(ws + (33u << 20));         // 32 MB

    prep_kernel<<<NCONV + NGATE, 256, 0, stream>>>(expert_w, wbf, x, gate_w, gate_b,
                                                   xbf, eids, gatesv);
    compact_kernel<<<1, 1024, 0, stream>>>(eids, gatesv, tok_list, gate_list, counts);

    moe_gemm_kernel<<<4096, 256, 0, stream>>>(xbf, wbf, expert_b,
                                              counts, tok_list, gate_list, out, part1);

    combine_kernel<<<N_TOK * HDIM / 4 / 256, 256, 0, stream>>>(out, part1);
}